// Round 3
// baseline (701.682 us; speedup 1.0000x reference)
//
#include <hip/hip_runtime.h>

#define TT 216
#define BB 16384
#define LOG2E 1.44269504088896340736f

typedef _Float16 h16;
typedef _Float16 half8 __attribute__((ext_vector_type(8)));
typedef float f32x4 __attribute__((ext_vector_type(4)));
// Vector types get char-TBAA in clang (alias everything) -> safe for LDS type
// punning. Scalar puns (unsigned long long) carry their own TBAA tag and get
// reordered across _Float16 stores (round-2 bug) -- never use scalar puns.

__device__ __forceinline__ float rcp_f(float v) { return __builtin_amdgcn_rcpf(v); }
__device__ __forceinline__ float ex2(float v)   { return __builtin_amdgcn_exp2f(v); }

// Gate preactivations arrive PRE-SCALED: pi,pf,po = -log2e*(preact), pg = 2*log2e*(preact).
// State cs = 2*log2e * c (pre-scaled cell state).
// sigmoid(i) = 1/(1+2^pi); tanh(g) = (Eg-2)/Eg, Eg = 1+2^pg.
// cs' = cs/Ef + 2L*(Eg-2)/(Ei*Eg) -> single rcp via common denominator.
// h = (Ec-2)/(Eo*Ec), Ec = 1+2^min(cs',60)  (clamp: keeps Eo*Ec finite).
__device__ __forceinline__ float lstm_up(float pi, float pf, float pg, float po, float& cs)
{
    float ei = ex2(pi), ef = ex2(pf), eg = ex2(pg), eo = ex2(po);
    float Ei = 1.f + ei, Ef = 1.f + ef, Eg = 1.f + eg, Eo = 1.f + eo;
    float EiEg = Ei * Eg;
    float G = fmaf(2.f * LOG2E, Eg, -4.f * LOG2E);   // 2L*(Eg-2)
    float N = fmaf(cs, EiEg, Ef * G);
    cs = N * rcp_f(Ef * EiEg);
    float pc = fminf(cs, 60.f);
    float Ec = 1.f + ex2(pc);
    return (Ec - 2.f) * rcp_f(Eo * Ec);
}

// ---------------- weight prep: fp32 -> fp16, fragment-ready, exp2-prescaled, bias-in-K ----
__global__ void prep_kernel(
    const float* __restrict__ Wih_f, const float* __restrict__ Whh_f,
    const float* __restrict__ bih_f, const float* __restrict__ bhh_f,
    const float* __restrict__ Wih_b, const float* __restrict__ Whh_b,
    const float* __restrict__ bih_b, const float* __restrict__ bhh_b,
    const float* __restrict__ Wih_m, const float* __restrict__ Whh_m,
    const float* __restrict__ bih_m, const float* __restrict__ bhh_m,
    h16* __restrict__ W1f, h16* __restrict__ W1b, h16* __restrict__ W2)
{
    int gtid = blockIdx.x * blockDim.x + threadIdx.x;
    int gs = gridDim.x * blockDim.x;
    // small LSTMs: W1[n=64][k=32]: k<8 x, 8..23 h, 24 bias (X col24==1), 25..31 zero
    for (int idx = gtid; idx < 64 * 32; idx += gs) {
        int n = idx >> 5, k = idx & 31;
        float a = ((n >> 4) == 2) ? 2.f * LOG2E : -LOG2E;
        float vf = 0.f, vb = 0.f;
        if (k < 8)        { vf = Wih_f[n * 8 + k];       vb = Wih_b[n * 8 + k]; }
        else if (k < 24)  { vf = Whh_f[n * 16 + k - 8];  vb = Whh_b[n * 16 + k - 8]; }
        else if (k == 24) { vf = bih_f[n] + bhh_f[n];    vb = bih_b[n] + bhh_b[n]; }
        W1f[idx] = (h16)(vf * a);
        W1b[idx] = (h16)(vb * a);
    }
    // middle LSTM: W2[n=256][k=128]: k<32 [hs_f|hs_b], 32..95 h2, 96 bias, 97..127 zero
    for (int idx = gtid; idx < 256 * 128; idx += gs) {
        int n = idx >> 7, k = idx & 127;
        float a = ((n >> 6) == 2) ? 2.f * LOG2E : -LOG2E;
        float v = 0.f;
        if (k < 32)       v = Wih_m[n * 32 + k];
        else if (k < 96)  v = Whh_m[n * 64 + k - 32];
        else if (k == 96) v = bih_m[n] + bhh_m[n];
        W2[idx] = (h16)(v * a);
    }
}

// ---------------- small LSTMs (fwd + bwd): ONE WAVE owns one (dir, 8-batch) recurrence ----
// v4: 8-BATCH windows -> 4096 waves = 4 chains/SIMD (was 2). The recurrence is
// latency-bound (SIMDs ~85% issue-idle at 2 chains/SIMD); doubling resident chains
// halves wall time even though half the MFMA rows / lstm_up lanes are now wasted
// (wave-wide instructions issue regardless of useful rows).
// No barriers. Per step: 4 gate MFMAs -> lane holds all 4 gate preacts for its rows ->
// 4 lstm_up -> in-wave C->A transpose via wave-private LDS (lgkmcnt only, no barrier).
// Rows 0..7 = real batches; rows 8..15 garbage (MFMA rows independent; results unused;
// OOB-able global reads clamped to BB-1).
// A-frag per lane (row=lane&15=batch, k=(lane>>4)*8+j):
//   q=0: x(t) (fp32, 3-step rotating prefetch, cvt)  q=1: h units 0..7  q=2: units 8..15
//   q=3: bias-one column (k=24) -- constant.
// hs store: q==1 lanes, batch b>>1 / half b&1 via second ds_read_b128 (contig 256B),
// batched 4 steps per group.
__global__ __launch_bounds__(256, 4) void small_lstm_kernel(
    const float* __restrict__ x,
    const float* __restrict__ h0f, const float* __restrict__ c0f,
    const float* __restrict__ h0b, const float* __restrict__ c0b,
    const h16* __restrict__ W1f, const h16* __restrict__ W1b,
    h16* __restrict__ hsf, h16* __restrict__ hsb)
{
    // wave-private transpose buffers: [wave][batch][unit], stride 24 h16 = 48B
    __shared__ __attribute__((aligned(16))) h16 hbuf[4][16][24];

    const int tid = threadIdx.x;
    const int wv = tid >> 6, lane = tid & 63;
    const int b = lane & 15, q = lane >> 4;      // b: A-row / C-col (batch or unit)

    const int wgid = blockIdx.x * 4 + wv;        // 4096 waves
    const int dir  = wgid & 1;
    const int base = (wgid >> 1) * 8;            // 8-batch window

    const float* h0 = dir ? h0b : h0f;
    const float* c0 = dir ? c0b : c0f;
    const h16* W1   = dir ? W1b : W1f;
    h16* hs = dir ? hsb : hsf;

    // clamped batch row for wave-wide loads (rows 8..15 are don't-care)
    const int bx = (base + b < BB) ? (base + b) : (BB - 1);

    // B fragments: one per gate, n = g*16 + col(b), k = q*8+j  (bias folded at k=24)
    half8 bf0 = *(const half8*)(W1 + (0 * 16 + b) * 32 + q * 8);
    half8 bf1 = *(const half8*)(W1 + (1 * 16 + b) * 32 + q * 8);
    half8 bf2 = *(const half8*)(W1 + (2 * 16 + b) * 32 + q * 8);
    half8 bf3 = *(const half8*)(W1 + (3 * 16 + b) * 32 + q * 8);

    // cell state: lane owns (row q*4+r, unit b); only rows<8 meaningful, clamp OOB reads
    int cr0 = base + q * 4 + 0; if (cr0 >= BB) cr0 = BB - 1;
    int cr1 = base + q * 4 + 1; if (cr1 >= BB) cr1 = BB - 1;
    int cr2 = base + q * 4 + 2; if (cr2 >= BB) cr2 = BB - 1;
    int cr3 = base + q * 4 + 3; if (cr3 >= BB) cr3 = BB - 1;
    float cs0 = c0[(size_t)cr0 * 16 + b] * (2.f * LOG2E);
    float cs1 = c0[(size_t)cr1 * 16 + b] * (2.f * LOG2E);
    float cs2 = c0[(size_t)cr2 * 16 + b] * (2.f * LOG2E);
    float cs3 = c0[(size_t)cr3 * 16 + b] * (2.f * LOG2E);

    const int t0 = dir ? (TT - 1) : 0;

    // initial A fragment (holds step u=0 data)
    half8 af;
    if (q == 0) {
        const float* xp = x + ((size_t)t0 * BB + bx) * 8;
        f32x4 u0 = *(const f32x4*)xp, u1 = *(const f32x4*)(xp + 4);
        af[0] = (h16)u0[0]; af[1] = (h16)u0[1]; af[2] = (h16)u0[2]; af[3] = (h16)u0[3];
        af[4] = (h16)u1[0]; af[5] = (h16)u1[1]; af[6] = (h16)u1[2]; af[7] = (h16)u1[3];
    } else if (q == 3) {
        af[0] = (h16)1.f;
        af[1] = (h16)0.f; af[2] = (h16)0.f; af[3] = (h16)0.f;
        af[4] = (h16)0.f; af[5] = (h16)0.f; af[6] = (h16)0.f; af[7] = (h16)0.f;
    } else {
        const float* hp = h0 + (size_t)bx * 16 + (q - 1) * 8;
        f32x4 u0 = *(const f32x4*)hp, u1 = *(const f32x4*)(hp + 4);
        af[0] = (h16)u0[0]; af[1] = (h16)u0[1]; af[2] = (h16)u0[2]; af[3] = (h16)u0[3];
        af[4] = (h16)u1[0]; af[5] = (h16)u1[1]; af[6] = (h16)u1[2]; af[7] = (h16)u1[3];
    }

    // 4-slot x prefetch file: slot k holds x for af-target step u with u%4==k.
    // Consumed at step s = u-1 (slot (j+1)&3), refilled at step s for u=s+4 (slot j).
    // All slot indices are compile-time constants after the 4x unroll (rule #20).
    f32x4 xr[4][2];
    if (q == 0) {
#pragma unroll
        for (int u = 1; u <= 3; ++u) {
            int tl = dir ? (TT - 1 - u) : u;
            const float* xp = x + ((size_t)tl * BB + bx) * 8;
            xr[u][0] = *(const f32x4*)xp;
            xr[u][1] = *(const f32x4*)(xp + 4);
        }
    }

    for (int it = 0; it < TT / 4; ++it) {        // 54 outer iters x 4 steps
        half8 hst[4];
#pragma unroll
        for (int j = 0; j < 4; ++j) {
            const int s = it * 4 + j;

            f32x4 z0 = {0.f, 0.f, 0.f, 0.f}, z1 = z0, z2 = z0, z3 = z0;
            z0 = __builtin_amdgcn_mfma_f32_16x16x32_f16(af, bf0, z0, 0, 0, 0);
            z1 = __builtin_amdgcn_mfma_f32_16x16x32_f16(af, bf1, z1, 0, 0, 0);
            z2 = __builtin_amdgcn_mfma_f32_16x16x32_f16(af, bf2, z2, 0, 0, 0);
            z3 = __builtin_amdgcn_mfma_f32_16x16x32_f16(af, bf3, z3, 0, 0, 0);

            // x for step s+1 from slot (j+1)&3 (loaded 3 steps ago)
            half8 xh;
            {
                const f32x4 u0 = xr[(j + 1) & 3][0], u1 = xr[(j + 1) & 3][1];
                xh[0] = (h16)u0[0]; xh[1] = (h16)u0[1]; xh[2] = (h16)u0[2]; xh[3] = (h16)u0[3];
                xh[4] = (h16)u1[0]; xh[5] = (h16)u1[1]; xh[6] = (h16)u1[2]; xh[7] = (h16)u1[3];
            }
            // refill slot j for af-target step s+4
            if (q == 0) {
                int ut = (s + 4 < TT) ? (s + 4) : (TT - 1);
                int tl = dir ? (TT - 1 - ut) : ut;
                const float* xp = x + ((size_t)tl * BB + bx) * 8;
                xr[j][0] = *(const f32x4*)xp;
                xr[j][1] = *(const f32x4*)(xp + 4);
            }

            float hh0 = lstm_up(z0[0], z1[0], z2[0], z3[0], cs0);
            float hh1 = lstm_up(z0[1], z1[1], z2[1], z3[1], cs1);
            float hh2 = lstm_up(z0[2], z1[2], z2[2], z3[2], cs2);
            float hh3 = lstm_up(z0[3], z1[3], z2[3], z3[3], cs3);

            // C->A transpose, wave-private: write [row][unit], read rows as half8.
            // Rows 8..15 (q>=2) are garbage lanes -- written & read but never used.
            hbuf[wv][q * 4 + 0][b] = (h16)hh0;
            hbuf[wv][q * 4 + 1][b] = (h16)hh1;
            hbuf[wv][q * 4 + 2][b] = (h16)hh2;
            hbuf[wv][q * 4 + 3][b] = (h16)hh3;
            asm volatile("s_waitcnt lgkmcnt(0)" ::: "memory");
            half8 hv = *(const half8*)&hbuf[wv][b][(q == 2) ? 8 : 0];
            // store-view read: batch b>>1, unit-half b&1 (used by q==1 lanes at flush)
            hst[j] = *(const half8*)&hbuf[wv][b >> 1][(b & 1) * 8];

            // next A fragment (q==3 keeps its constant bias column forever)
            if (q == 0)      af = xh;
            else if (q != 3) af = hv;
        }
        // batched hs stores: q==1 lanes cover [8 batch][16 units] contiguously (256B)
        if (q == 1) {
#pragma unroll
            for (int j = 0; j < 4; ++j) {
                int s = it * 4 + j;
                int t = dir ? (TT - 1 - s) : s;
                *(half8*)(hs + ((size_t)t * BB + base + (b >> 1)) * 16 + (b & 1) * 8) = hst[j];
            }
        }
    }
}

// ---------------- middle LSTM + dense, 16-batch blocks, K=96 + bias-in-acc ---------------
// block = 256 (4 waves): wave w handles units [16w,16w+16) for all 4 gates.
// K-tile 3 (k=96..127: bias col + zeros) removed -> accumulators init'd with the (h16,
// pre-scaled) bias instead: 12 MFMA/step/wave, 3 ds_read_b128.
// X[16][96] = [hs_f|hs_b|h2] fp16 (+pad to 104; pad cols never read), double-buffered.
// One barrier per step. Dense out(t-1) = 2 extra MFMA on wave 3 over X(t) k=32..95.
// (setprio around MFMAs measured -6us consistent regression in r2 -> removed.)
__global__ __launch_bounds__(256, 4) void mid_lstm_kernel(
    const h16* __restrict__ hsf, const h16* __restrict__ hsb,
    const float* __restrict__ h0m, const float* __restrict__ c0m,
    const h16* __restrict__ W2,
    const float* __restrict__ Wd, const float* __restrict__ bdp,
    float* __restrict__ out)
{
    __shared__ __attribute__((aligned(16))) h16 Xs[2][16][104];
    __shared__ float outbuf[16][55];

    const int tid = threadIdx.x;
    const int base = blockIdx.x * 16;
    const int wv = tid >> 6, lane = tid & 63, col = lane & 15, q = lane >> 4;

    half8 bfr[4][3];
    float bp[4];
#pragma unroll
    for (int p = 0; p < 4; ++p) {
        int n = p * 64 + wv * 16 + col;
#pragma unroll
        for (int kt = 0; kt < 3; ++kt)
            bfr[p][kt] = *(const half8*)(W2 + (size_t)n * 128 + kt * 32 + q * 8);
        bp[p] = (float)W2[(size_t)n * 128 + 96];   // pre-scaled bias (h16-rounded)
    }
    half8 dfr[2];   // dense B-fragment: column 0 = wd over k in [32,96)
#pragma unroll
    for (int kt = 0; kt < 2; ++kt)
#pragma unroll
        for (int j = 0; j < 8; ++j)
            dfr[kt][j] = (col == 0) ? (h16)Wd[kt * 32 + q * 8 + j] : (h16)0.f;
    const float bdv = bdp[0];

    float cs[4];
#pragma unroll
    for (int r = 0; r < 4; ++r)
        cs[r] = c0m[(size_t)(base + q * 4 + r) * 64 + wv * 16 + col] * (2.f * LOG2E);

    const h16* hsrc = (wv == 1) ? hsb : hsf;
    const int srow = lane >> 1, su8 = (lane & 1) * 8;
    // initial staging: hs(0) + h0m into Xs[0]   (pad cols 96..103 are never read)
    if (wv < 2 && lane < 32) {
        uint4 v = *(const uint4*)(hsrc + ((size_t)0 * BB + base + srow) * 16 + su8);
        *(uint4*)&Xs[0][srow][wv * 16 + su8] = v;
    }
    {
        int row = tid >> 4, u4 = (tid & 15) * 4;
        float4 v = *(const float4*)(h0m + (size_t)(base + row) * 64 + u4);
        h16* d = &Xs[0][row][32 + u4];
        d[0] = (h16)v.x; d[1] = (h16)v.y; d[2] = (h16)v.z; d[3] = (h16)v.w;
    }
    // hs register pipeline (2 steps deep) on waves 0,1
    uint4 ra, rb;
    if (wv < 2 && lane < 32) {
        ra = *(const uint4*)(hsrc + ((size_t)1 * BB + base + srow) * 16 + su8);
        rb = *(const uint4*)(hsrc + ((size_t)2 * BB + base + srow) * 16 + su8);
    }
    __syncthreads();

    for (int t = 0; t < TT; ++t) {
        const int cur = t & 1, nxt = cur ^ 1;
        if (wv < 2 && lane < 32) {
            if (t < TT - 1)
                *(uint4*)&Xs[nxt][srow][wv * 16 + su8] = ra;   // hs(t+1)
            ra = rb;
            int tl = (t + 3 < TT) ? (t + 3) : (TT - 1);
            rb = *(const uint4*)(hsrc + ((size_t)tl * BB + base + srow) * 16 + su8);
        }
        half8 af[3];
#pragma unroll
        for (int kt = 0; kt < 3; ++kt)
            af[kt] = *(const half8*)&Xs[cur][col][kt * 32 + q * 8];
        // dense for out(t-1): X(t) k=32..95 holds h2(t-1)
        if (wv == 3 && t > 0) {
            f32x4 z = {0.f, 0.f, 0.f, 0.f};
            z = __builtin_amdgcn_mfma_f32_16x16x32_f16(af[1], dfr[0], z, 0, 0, 0);
            z = __builtin_amdgcn_mfma_f32_16x16x32_f16(af[2], dfr[1], z, 0, 0, 0);
            if (col == 0) {
                int tc = (t - 1) % 54;
#pragma unroll
                for (int r = 0; r < 4; ++r)
                    outbuf[q * 4 + r][tc] = z[r] + bdv;
            }
        }
        f32x4 acc[4];
#pragma unroll
        for (int p = 0; p < 4; ++p) {
            f32x4 z = {bp[p], bp[p], bp[p], bp[p]};
            z = __builtin_amdgcn_mfma_f32_16x16x32_f16(af[0], bfr[p][0], z, 0, 0, 0);
            z = __builtin_amdgcn_mfma_f32_16x16x32_f16(af[1], bfr[p][1], z, 0, 0, 0);
            z = __builtin_amdgcn_mfma_f32_16x16x32_f16(af[2], bfr[p][2], z, 0, 0, 0);
            acc[p] = z;
        }
#pragma unroll
        for (int r = 0; r < 4; ++r) {
            float h = lstm_up(acc[0][r], acc[1][r], acc[2][r], acc[3][r], cs[r]);
            Xs[nxt][q * 4 + r][32 + wv * 16 + col] = (h16)h;
        }
        if (t > 0 && (t % 54) == 0) {   // flush out(t-54 .. t-1)
            __syncthreads();
            int off = t - 54;
            for (int idx = tid; idx < 16 * 54; idx += 256) {
                int row = idx / 54, cc = idx - row * 54;
                out[(size_t)(base + row) * TT + off + cc] = outbuf[row][cc];
            }
        }
        __syncthreads();
    }
    // epilogue: out(215) from Xs[0] (h2(215) staged there at t=215)
    if (wv == 3) {
        half8 a1 = *(const half8*)&Xs[0][col][32 + q * 8];
        half8 a2 = *(const half8*)&Xs[0][col][64 + q * 8];
        f32x4 z = {0.f, 0.f, 0.f, 0.f};
        z = __builtin_amdgcn_mfma_f32_16x16x32_f16(a1, dfr[0], z, 0, 0, 0);
        z = __builtin_amdgcn_mfma_f32_16x16x32_f16(a2, dfr[1], z, 0, 0, 0);
        if (col == 0)
#pragma unroll
            for (int r = 0; r < 4; ++r)
                outbuf[q * 4 + r][53] = z[r] + bdv;
    }
    __syncthreads();
    for (int idx = tid; idx < 16 * 54; idx += 256) {
        int row = idx / 54, cc = idx - row * 54;
        out[(size_t)(base + row) * TT + 162 + cc] = outbuf[row][cc];
    }
}

extern "C" void kernel_launch(void* const* d_in, const int* in_sizes, int n_in,
                              void* d_out, int out_size, void* d_ws, size_t ws_size,
                              hipStream_t stream)
{
    const float* x     = (const float*)d_in[0];
    const float* h0f   = (const float*)d_in[1];
    const float* c0f   = (const float*)d_in[2];
    const float* h0b   = (const float*)d_in[3];
    const float* c0b   = (const float*)d_in[4];
    const float* h0m   = (const float*)d_in[5];
    const float* c0m   = (const float*)d_in[6];
    const float* Wih_f = (const float*)d_in[7];
    const float* Whh_f = (const float*)d_in[8];
    const float* bih_f = (const float*)d_in[9];
    const float* bhh_f = (const float*)d_in[10];
    const float* Wih_b = (const float*)d_in[11];
    const float* Whh_b = (const float*)d_in[12];
    const float* bih_b = (const float*)d_in[13];
    const float* bhh_b = (const float*)d_in[14];
    const float* Wih_m = (const float*)d_in[15];
    const float* Whh_m = (const float*)d_in[16];
    const float* bih_m = (const float*)d_in[17];
    const float* bhh_m = (const float*)d_in[18];
    const float* Wd    = (const float*)d_in[19];
    const float* bd    = (const float*)d_in[20];

    char* ws = (char*)d_ws;
    h16* W1f = (h16*)(ws + 0);        // 64*32*2    = 4096
    h16* W1b = (h16*)(ws + 4096);     // 4096
    h16* W2  = (h16*)(ws + 8192);     // 256*128*2  = 65536
    h16* hsf = (h16*)(ws + 73728);                               // [T][B][16] fp16
    h16* hsb = (h16*)(ws + 73728 + (size_t)TT * BB * 16 * 2);    // [T][B][16] fp16

    prep_kernel<<<64, 256, 0, stream>>>(Wih_f, Whh_f, bih_f, bhh_f,
                                        Wih_b, Whh_b, bih_b, bhh_b,
                                        Wih_m, Whh_m, bih_m, bhh_m,
                                        W1f, W1b, W2);
    small_lstm_kernel<<<1024, 256, 0, stream>>>(x, h0f, c0f, h0b, c0b,
                                                W1f, W1b, hsf, hsb);
    mid_lstm_kernel<<<1024, 256, 0, stream>>>(hsf, hsb, h0m, c0m, W2,
                                              Wd, bd, (float*)d_out);
}

// Round 4
// 680.353 us; speedup vs baseline: 1.0314x; 1.0314x over previous
//
#include <hip/hip_runtime.h>

#define TT 216
#define BB 16384
#define LOG2E 1.44269504088896340736f

typedef _Float16 h16;
typedef _Float16 half8 __attribute__((ext_vector_type(8)));
typedef float f32x4 __attribute__((ext_vector_type(4)));
// Vector types get char-TBAA in clang (alias everything) -> safe for LDS type
// punning. Scalar puns (unsigned long long) carry their own TBAA tag and get
// reordered across _Float16 stores (round-2 bug) -- never use scalar puns.

__device__ __forceinline__ float rcp_f(float v) { return __builtin_amdgcn_rcpf(v); }
__device__ __forceinline__ float ex2(float v)   { return __builtin_amdgcn_exp2f(v); }

// Gate preactivations arrive PRE-SCALED: pi,pf,po = -log2e*(preact), pg = 2*log2e*(preact).
// State cs = 2*log2e * c (pre-scaled cell state).
// sigmoid(i) = 1/(1+2^pi); tanh(g) = (Eg-2)/Eg, Eg = 1+2^pg.
// cs' = cs/Ef + 2L*(Eg-2)/(Ei*Eg) -> single rcp via common denominator.
// h = (Ec-2)/(Eo*Ec), Ec = 1+2^min(cs',60)  (clamp: keeps Eo*Ec finite).
__device__ __forceinline__ float lstm_up(float pi, float pf, float pg, float po, float& cs)
{
    float ei = ex2(pi), ef = ex2(pf), eg = ex2(pg), eo = ex2(po);
    float Ei = 1.f + ei, Ef = 1.f + ef, Eg = 1.f + eg, Eo = 1.f + eo;
    float EiEg = Ei * Eg;
    float G = fmaf(2.f * LOG2E, Eg, -4.f * LOG2E);   // 2L*(Eg-2)
    float N = fmaf(cs, EiEg, Ef * G);
    cs = N * rcp_f(Ef * EiEg);
    float pc = fminf(cs, 60.f);
    float Ec = 1.f + ex2(pc);
    return (Ec - 2.f) * rcp_f(Eo * Ec);
}

// ---------------- weight prep: fp32 -> fp16, fragment-ready, exp2-prescaled, bias-in-K ----
__global__ void prep_kernel(
    const float* __restrict__ Wih_f, const float* __restrict__ Whh_f,
    const float* __restrict__ bih_f, const float* __restrict__ bhh_f,
    const float* __restrict__ Wih_b, const float* __restrict__ Whh_b,
    const float* __restrict__ bih_b, const float* __restrict__ bhh_b,
    const float* __restrict__ Wih_m, const float* __restrict__ Whh_m,
    const float* __restrict__ bih_m, const float* __restrict__ bhh_m,
    h16* __restrict__ W1f, h16* __restrict__ W1b, h16* __restrict__ W2)
{
    int gtid = blockIdx.x * blockDim.x + threadIdx.x;
    int gs = gridDim.x * blockDim.x;
    // small LSTMs: W1[n=64][k=32]: k<8 x, 8..23 h, 24 bias (X col24==1), 25..31 zero
    for (int idx = gtid; idx < 64 * 32; idx += gs) {
        int n = idx >> 5, k = idx & 31;
        float a = ((n >> 4) == 2) ? 2.f * LOG2E : -LOG2E;
        float vf = 0.f, vb = 0.f;
        if (k < 8)        { vf = Wih_f[n * 8 + k];       vb = Wih_b[n * 8 + k]; }
        else if (k < 24)  { vf = Whh_f[n * 16 + k - 8];  vb = Whh_b[n * 16 + k - 8]; }
        else if (k == 24) { vf = bih_f[n] + bhh_f[n];    vb = bih_b[n] + bhh_b[n]; }
        W1f[idx] = (h16)(vf * a);
        W1b[idx] = (h16)(vb * a);
    }
    // middle LSTM: W2[n=256][k=128]: k<32 [hs_f|hs_b], 32..95 h2, 96 bias, 97..127 zero
    for (int idx = gtid; idx < 256 * 128; idx += gs) {
        int n = idx >> 7, k = idx & 127;
        float a = ((n >> 6) == 2) ? 2.f * LOG2E : -LOG2E;
        float v = 0.f;
        if (k < 32)       v = Wih_m[n * 32 + k];
        else if (k < 96)  v = Whh_m[n * 64 + k - 32];
        else if (k == 96) v = bih_m[n] + bhh_m[n];
        W2[idx] = (h16)(v * a);
    }
}

// ---------------- small LSTMs (fwd + bwd): ONE WAVE owns one (dir, 16-batch) recurrence ---
// (r2 version -- best measured ~291us. r3's 8-batch/half-wasted-lanes variant regressed
// +60us: never pay doubled issue for chain count.)
// No barriers. Per step: 4 gate MFMAs -> lane holds all 4 gate preacts -> 4 lstm_up ->
// in-wave C->A transpose via wave-private LDS (lgkmcnt only).
// A-frag per lane (row=lane&15=batch, k=(lane>>4)*8+j):
//   q=0: x(t) (fp32, 3-step rotating prefetch, cvt)  q=1: h units 0..7  q=2: units 8..15
//   q=3: bias-one column (k=24) -- constant.
__global__ __launch_bounds__(256, 2) void small_lstm_kernel(
    const float* __restrict__ x,
    const float* __restrict__ h0f, const float* __restrict__ c0f,
    const float* __restrict__ h0b, const float* __restrict__ c0b,
    const h16* __restrict__ W1f, const h16* __restrict__ W1b,
    h16* __restrict__ hsf, h16* __restrict__ hsb)
{
    __shared__ __attribute__((aligned(16))) h16 hbuf[4][16][24];

    const int tid = threadIdx.x;
    const int wv = tid >> 6, lane = tid & 63;
    const int b = lane & 15, q = lane >> 4;

    const int wgid = blockIdx.x * 4 + wv;        // 2048 waves
    const int dir  = wgid & 1;
    const int base = (wgid >> 1) * 16;

    const float* h0 = dir ? h0b : h0f;
    const float* c0 = dir ? c0b : c0f;
    const h16* W1   = dir ? W1b : W1f;
    h16* hs = dir ? hsb : hsf;

    half8 bf0 = *(const half8*)(W1 + (0 * 16 + b) * 32 + q * 8);
    half8 bf1 = *(const half8*)(W1 + (1 * 16 + b) * 32 + q * 8);
    half8 bf2 = *(const half8*)(W1 + (2 * 16 + b) * 32 + q * 8);
    half8 bf3 = *(const half8*)(W1 + (3 * 16 + b) * 32 + q * 8);

    float cs0 = c0[(size_t)(base + q * 4 + 0) * 16 + b] * (2.f * LOG2E);
    float cs1 = c0[(size_t)(base + q * 4 + 1) * 16 + b] * (2.f * LOG2E);
    float cs2 = c0[(size_t)(base + q * 4 + 2) * 16 + b] * (2.f * LOG2E);
    float cs3 = c0[(size_t)(base + q * 4 + 3) * 16 + b] * (2.f * LOG2E);

    const int t0 = dir ? (TT - 1) : 0;

    half8 af;
    if (q == 0) {
        const float* xp = x + ((size_t)t0 * BB + base + b) * 8;
        f32x4 u0 = *(const f32x4*)xp, u1 = *(const f32x4*)(xp + 4);
        af[0] = (h16)u0[0]; af[1] = (h16)u0[1]; af[2] = (h16)u0[2]; af[3] = (h16)u0[3];
        af[4] = (h16)u1[0]; af[5] = (h16)u1[1]; af[6] = (h16)u1[2]; af[7] = (h16)u1[3];
    } else if (q == 3) {
        af[0] = (h16)1.f;
        af[1] = (h16)0.f; af[2] = (h16)0.f; af[3] = (h16)0.f;
        af[4] = (h16)0.f; af[5] = (h16)0.f; af[6] = (h16)0.f; af[7] = (h16)0.f;
    } else {
        const float* hp = h0 + (size_t)(base + b) * 16 + (q - 1) * 8;
        f32x4 u0 = *(const f32x4*)hp, u1 = *(const f32x4*)(hp + 4);
        af[0] = (h16)u0[0]; af[1] = (h16)u0[1]; af[2] = (h16)u0[2]; af[3] = (h16)u0[3];
        af[4] = (h16)u1[0]; af[5] = (h16)u1[1]; af[6] = (h16)u1[2]; af[7] = (h16)u1[3];
    }

    // 4-slot x prefetch file: slot k holds x for af-target step u with u%4==k.
    // All slot indices are compile-time constants after the 4x unroll (rule #20).
    f32x4 xr[4][2];
    if (q == 0) {
#pragma unroll
        for (int u = 1; u <= 3; ++u) {
            int tl = dir ? (TT - 1 - u) : u;
            const float* xp = x + ((size_t)tl * BB + base + b) * 8;
            xr[u][0] = *(const f32x4*)xp;
            xr[u][1] = *(const f32x4*)(xp + 4);
        }
    }

    for (int it = 0; it < TT / 4; ++it) {        // 54 outer iters x 4 steps
        half8 hst[4];
#pragma unroll
        for (int j = 0; j < 4; ++j) {
            const int s = it * 4 + j;

            f32x4 z0 = {0.f, 0.f, 0.f, 0.f}, z1 = z0, z2 = z0, z3 = z0;
            z0 = __builtin_amdgcn_mfma_f32_16x16x32_f16(af, bf0, z0, 0, 0, 0);
            z1 = __builtin_amdgcn_mfma_f32_16x16x32_f16(af, bf1, z1, 0, 0, 0);
            z2 = __builtin_amdgcn_mfma_f32_16x16x32_f16(af, bf2, z2, 0, 0, 0);
            z3 = __builtin_amdgcn_mfma_f32_16x16x32_f16(af, bf3, z3, 0, 0, 0);

            half8 xh;
            {
                const f32x4 u0 = xr[(j + 1) & 3][0], u1 = xr[(j + 1) & 3][1];
                xh[0] = (h16)u0[0]; xh[1] = (h16)u0[1]; xh[2] = (h16)u0[2]; xh[3] = (h16)u0[3];
                xh[4] = (h16)u1[0]; xh[5] = (h16)u1[1]; xh[6] = (h16)u1[2]; xh[7] = (h16)u1[3];
            }
            if (q == 0) {
                int ut = (s + 4 < TT) ? (s + 4) : (TT - 1);
                int tl = dir ? (TT - 1 - ut) : ut;
                const float* xp = x + ((size_t)tl * BB + base + b) * 8;
                xr[j][0] = *(const f32x4*)xp;
                xr[j][1] = *(const f32x4*)(xp + 4);
            }

            float hh0 = lstm_up(z0[0], z1[0], z2[0], z3[0], cs0);
            float hh1 = lstm_up(z0[1], z1[1], z2[1], z3[1], cs1);
            float hh2 = lstm_up(z0[2], z1[2], z2[2], z3[2], cs2);
            float hh3 = lstm_up(z0[3], z1[3], z2[3], z3[3], cs3);

            hbuf[wv][q * 4 + 0][b] = (h16)hh0;
            hbuf[wv][q * 4 + 1][b] = (h16)hh1;
            hbuf[wv][q * 4 + 2][b] = (h16)hh2;
            hbuf[wv][q * 4 + 3][b] = (h16)hh3;
            asm volatile("s_waitcnt lgkmcnt(0)" ::: "memory");
            half8 hv = *(const half8*)&hbuf[wv][b][(q == 2) ? 8 : 0];
            hst[j] = hv;

            if (q == 0)      af = xh;
            else if (q != 3) af = hv;
        }
        if (q == 1 || q == 2) {
#pragma unroll
            for (int j = 0; j < 4; ++j) {
                int s = it * 4 + j;
                int t = dir ? (TT - 1 - s) : s;
                *(half8*)(hs + ((size_t)t * BB + base + b) * 16 + (q - 1) * 8) = hst[j];
            }
        }
    }
}

// ---------------- middle LSTM + dense: 2 windows (32 batches) per block, ILP ------------
// v2: block owns batches [32b, 32b+32) as windows A=[+0,+16) B=[+16,+32). Per step each
// wave computes its 16-unit slice for BOTH windows (24 MFMA + 8 lstm_up), then ONE barrier
// covers both. A's lstm_up latency hides under B's MFMAs inside the same wave (useful ILP,
// unlike r3's wasted-lane trade). 512 blocks x 4 waves = 2 waves/SIMD x 2 chains each.
// Staging: wave w stages (window w>>1, dir w&1). Dense out on wave 1 (A) / wave 3 (B).
// K=96 + bias-in-acc (12 MFMA per window-step); all per-window state explicitly split
// (csA/csB, accA/accB, afA/afB) so every index is compile-time static (rule #20).
__global__ __launch_bounds__(256, 2) void mid_lstm_kernel(
    const h16* __restrict__ hsf, const h16* __restrict__ hsb,
    const float* __restrict__ h0m, const float* __restrict__ c0m,
    const h16* __restrict__ W2,
    const float* __restrict__ Wd, const float* __restrict__ bdp,
    float* __restrict__ out)
{
    __shared__ __attribute__((aligned(16))) h16 Xs[2][2][16][104];  // [win][buf][row][col]
    __shared__ float outbuf[2][16][55];

    const int tid = threadIdx.x;
    const int base = blockIdx.x * 32;
    const int wv = tid >> 6, lane = tid & 63, col = lane & 15, q = lane >> 4;

    half8 bfr[4][3];
    float bp[4];
#pragma unroll
    for (int p = 0; p < 4; ++p) {
        int n = p * 64 + wv * 16 + col;
#pragma unroll
        for (int kt = 0; kt < 3; ++kt)
            bfr[p][kt] = *(const half8*)(W2 + (size_t)n * 128 + kt * 32 + q * 8);
        bp[p] = (float)W2[(size_t)n * 128 + 96];   // pre-scaled bias (h16-rounded)
    }
    half8 dfr[2];   // dense B-fragment: column 0 = wd over k in [32,96)
#pragma unroll
    for (int kt = 0; kt < 2; ++kt)
#pragma unroll
        for (int j = 0; j < 8; ++j)
            dfr[kt][j] = (col == 0) ? (h16)Wd[kt * 32 + q * 8 + j] : (h16)0.f;
    const float bdv = bdp[0];

    float csA[4], csB[4];
#pragma unroll
    for (int r = 0; r < 4; ++r) {
        csA[r] = c0m[(size_t)(base + q * 4 + r) * 64 + wv * 16 + col] * (2.f * LOG2E);
        csB[r] = c0m[(size_t)(base + 16 + q * 4 + r) * 64 + wv * 16 + col] * (2.f * LOG2E);
    }

    // staging assignment: wave w -> (window w>>1, src w&1)
    const h16* hsrc = (wv & 1) ? hsb : hsf;
    const int mywin = wv >> 1;
    const int srow = lane >> 1, su8 = (lane & 1) * 8;
    const int scol = (wv & 1) * 16 + su8;
    const int grow = base + mywin * 16 + srow;      // global batch row staged by this lane

    // initial staging: hs(0) for both windows/dirs + h0m into Xs[*][0]
    if (lane < 32) {
        uint4 v = *(const uint4*)(hsrc + ((size_t)0 * BB + grow) * 16 + su8);
        *(uint4*)&Xs[mywin][0][srow][scol] = v;
    }
    {
        int row = tid >> 4, u4 = (tid & 15) * 4;
        float4 vA = *(const float4*)(h0m + (size_t)(base + row) * 64 + u4);
        h16* dA = &Xs[0][0][row][32 + u4];
        dA[0] = (h16)vA.x; dA[1] = (h16)vA.y; dA[2] = (h16)vA.z; dA[3] = (h16)vA.w;
        float4 vB = *(const float4*)(h0m + (size_t)(base + 16 + row) * 64 + u4);
        h16* dB = &Xs[1][0][row][32 + u4];
        dB[0] = (h16)vB.x; dB[1] = (h16)vB.y; dB[2] = (h16)vB.z; dB[3] = (h16)vB.w;
    }
    // hs register pipeline (2 steps deep), all 4 waves stage their (window,dir)
    uint4 ra, rb;
    if (lane < 32) {
        ra = *(const uint4*)(hsrc + ((size_t)1 * BB + grow) * 16 + su8);
        rb = *(const uint4*)(hsrc + ((size_t)2 * BB + grow) * 16 + su8);
    }
    __syncthreads();

    for (int t = 0; t < TT; ++t) {
        const int cur = t & 1, nxt = cur ^ 1;
        if (lane < 32) {
            if (t < TT - 1)
                *(uint4*)&Xs[mywin][nxt][srow][scol] = ra;   // hs(t+1)
            ra = rb;
            int tl = (t + 3 < TT) ? (t + 3) : (TT - 1);
            rb = *(const uint4*)(hsrc + ((size_t)tl * BB + grow) * 16 + su8);
        }
        half8 afA[3], afB[3];
#pragma unroll
        for (int kt = 0; kt < 3; ++kt) {
            afA[kt] = *(const half8*)&Xs[0][cur][col][kt * 32 + q * 8];
            afB[kt] = *(const half8*)&Xs[1][cur][col][kt * 32 + q * 8];
        }
        // dense for out(t-1): wave 1 -> window A, wave 3 -> window B
        if ((wv & 1) && t > 0) {
            half8 a1 = (wv == 1) ? afA[1] : afB[1];
            half8 a2 = (wv == 1) ? afA[2] : afB[2];
            f32x4 z = {0.f, 0.f, 0.f, 0.f};
            z = __builtin_amdgcn_mfma_f32_16x16x32_f16(a1, dfr[0], z, 0, 0, 0);
            z = __builtin_amdgcn_mfma_f32_16x16x32_f16(a2, dfr[1], z, 0, 0, 0);
            if (col == 0) {
                int tc = (t - 1) % 54;
#pragma unroll
                for (int r = 0; r < 4; ++r)
                    outbuf[wv >> 1][q * 4 + r][tc] = z[r] + bdv;
            }
        }
        f32x4 accA[4], accB[4];
#pragma unroll
        for (int p = 0; p < 4; ++p) {
            f32x4 z = {bp[p], bp[p], bp[p], bp[p]};
            z = __builtin_amdgcn_mfma_f32_16x16x32_f16(afA[0], bfr[p][0], z, 0, 0, 0);
            z = __builtin_amdgcn_mfma_f32_16x16x32_f16(afA[1], bfr[p][1], z, 0, 0, 0);
            z = __builtin_amdgcn_mfma_f32_16x16x32_f16(afA[2], bfr[p][2], z, 0, 0, 0);
            accA[p] = z;
        }
#pragma unroll
        for (int p = 0; p < 4; ++p) {
            f32x4 z = {bp[p], bp[p], bp[p], bp[p]};
            z = __builtin_amdgcn_mfma_f32_16x16x32_f16(afB[0], bfr[p][0], z, 0, 0, 0);
            z = __builtin_amdgcn_mfma_f32_16x16x32_f16(afB[1], bfr[p][1], z, 0, 0, 0);
            z = __builtin_amdgcn_mfma_f32_16x16x32_f16(afB[2], bfr[p][2], z, 0, 0, 0);
            accB[p] = z;
        }
#pragma unroll
        for (int r = 0; r < 4; ++r) {
            float hA = lstm_up(accA[0][r], accA[1][r], accA[2][r], accA[3][r], csA[r]);
            Xs[0][nxt][q * 4 + r][32 + wv * 16 + col] = (h16)hA;
        }
#pragma unroll
        for (int r = 0; r < 4; ++r) {
            float hB = lstm_up(accB[0][r], accB[1][r], accB[2][r], accB[3][r], csB[r]);
            Xs[1][nxt][q * 4 + r][32 + wv * 16 + col] = (h16)hB;
        }
        if (t > 0 && (t % 54) == 0) {   // flush out(t-54 .. t-1) for both windows
            __syncthreads();
            int off = t - 54;
            for (int idx = tid; idx < 2 * 16 * 54; idx += 256) {
                int w = idx / (16 * 54), rem = idx - w * 16 * 54;
                int row = rem / 54, cc = rem - row * 54;
                out[(size_t)(base + w * 16 + row) * TT + off + cc] = outbuf[w][row][cc];
            }
        }
        __syncthreads();
    }
    // epilogue: out(215) from Xs[*][0] (h2(215) staged there at t=215)
    if (wv & 1) {
        const int w = wv >> 1;
        half8 a1 = *(const half8*)&Xs[w][0][col][32 + q * 8];
        half8 a2 = *(const half8*)&Xs[w][0][col][64 + q * 8];
        f32x4 z = {0.f, 0.f, 0.f, 0.f};
        z = __builtin_amdgcn_mfma_f32_16x16x32_f16(a1, dfr[0], z, 0, 0, 0);
        z = __builtin_amdgcn_mfma_f32_16x16x32_f16(a2, dfr[1], z, 0, 0, 0);
        if (col == 0)
#pragma unroll
            for (int r = 0; r < 4; ++r)
                outbuf[w][q * 4 + r][53] = z[r] + bdv;
    }
    __syncthreads();
    for (int idx = tid; idx < 2 * 16 * 54; idx += 256) {
        int w = idx / (16 * 54), rem = idx - w * 16 * 54;
        int row = rem / 54, cc = rem - row * 54;
        out[(size_t)(base + w * 16 + row) * TT + 162 + cc] = outbuf[w][row][cc];
    }
}

extern "C" void kernel_launch(void* const* d_in, const int* in_sizes, int n_in,
                              void* d_out, int out_size, void* d_ws, size_t ws_size,
                              hipStream_t stream)
{
    const float* x     = (const float*)d_in[0];
    const float* h0f   = (const float*)d_in[1];
    const float* c0f   = (const float*)d_in[2];
    const float* h0b   = (const float*)d_in[3];
    const float* c0b   = (const float*)d_in[4];
    const float* h0m   = (const float*)d_in[5];
    const float* c0m   = (const float*)d_in[6];
    const float* Wih_f = (const float*)d_in[7];
    const float* Whh_f = (const float*)d_in[8];
    const float* bih_f = (const float*)d_in[9];
    const float* bhh_f = (const float*)d_in[10];
    const float* Wih_b = (const float*)d_in[11];
    const float* Whh_b = (const float*)d_in[12];
    const float* bih_b = (const float*)d_in[13];
    const float* bhh_b = (const float*)d_in[14];
    const float* Wih_m = (const float*)d_in[15];
    const float* Whh_m = (const float*)d_in[16];
    const float* bih_m = (const float*)d_in[17];
    const float* bhh_m = (const float*)d_in[18];
    const float* Wd    = (const float*)d_in[19];
    const float* bd    = (const float*)d_in[20];

    char* ws = (char*)d_ws;
    h16* W1f = (h16*)(ws + 0);        // 64*32*2    = 4096
    h16* W1b = (h16*)(ws + 4096);     // 4096
    h16* W2  = (h16*)(ws + 8192);     // 256*128*2  = 65536
    h16* hsf = (h16*)(ws + 73728);                               // [T][B][16] fp16
    h16* hsb = (h16*)(ws + 73728 + (size_t)TT * BB * 16 * 2);    // [T][B][16] fp16

    prep_kernel<<<64, 256, 0, stream>>>(Wih_f, Whh_f, bih_f, bhh_f,
                                        Wih_b, Whh_b, bih_b, bhh_b,
                                        Wih_m, Whh_m, bih_m, bhh_m,
                                        W1f, W1b, W2);
    small_lstm_kernel<<<512, 256, 0, stream>>>(x, h0f, c0f, h0b, c0b,
                                               W1f, W1b, hsf, hsb);
    mid_lstm_kernel<<<512, 256, 0, stream>>>(hsf, hsb, h0m, c0m, W2,
                                             Wd, bd, (float*)d_out);
}

// Round 5
// 609.086 us; speedup vs baseline: 1.1520x; 1.1170x over previous
//
#include <hip/hip_runtime.h>

#define TT 216
#define BB 16384
#define LOG2E 1.44269504088896340736f

typedef _Float16 h16;
typedef _Float16 half8 __attribute__((ext_vector_type(8)));
typedef _Float16 h4 __attribute__((ext_vector_type(4)));
typedef float f32x4 __attribute__((ext_vector_type(4)));
typedef int i2 __attribute__((ext_vector_type(2)));
typedef int i4 __attribute__((ext_vector_type(4)));
// Vector types get char-TBAA in clang (alias everything) -> safe for LDS type
// punning. Scalar puns (unsigned long long) carry their own TBAA tag and get
// reordered across _Float16 stores (round-2 bug) -- never use scalar puns.

__device__ __forceinline__ float rcp_f(float v) { return __builtin_amdgcn_rcpf(v); }
__device__ __forceinline__ float ex2(float v)   { return __builtin_amdgcn_exp2f(v); }

// Gate preactivations arrive PRE-SCALED: pi,pf,po = -log2e*(preact), pg = 2*log2e*(preact).
// State cs = 2*log2e * c (pre-scaled cell state).
// sigmoid(i) = 1/(1+2^pi); tanh(g) = (Eg-2)/Eg, Eg = 1+2^pg.
// cs' = cs/Ef + 2L*(Eg-2)/(Ei*Eg) -> single rcp via common denominator.
// h = (Ec-2)/(Eo*Ec), Ec = 1+2^min(cs',60)  (clamp: keeps Eo*Ec finite).
__device__ __forceinline__ float lstm_up(float pi, float pf, float pg, float po, float& cs)
{
    float ei = ex2(pi), ef = ex2(pf), eg = ex2(pg), eo = ex2(po);
    float Ei = 1.f + ei, Ef = 1.f + ef, Eg = 1.f + eg, Eo = 1.f + eo;
    float EiEg = Ei * Eg;
    float G = fmaf(2.f * LOG2E, Eg, -4.f * LOG2E);   // 2L*(Eg-2)
    float N = fmaf(cs, EiEg, Ef * G);
    cs = N * rcp_f(Ef * EiEg);
    float pc = fminf(cs, 60.f);
    float Ec = 1.f + ex2(pc);
    return (Ec - 2.f) * rcp_f(Eo * Ec);
}

// ---------------- weight prep: fp32 -> fp16, fragment-ready, exp2-prescaled, bias-in-K ----
__global__ void prep_kernel(
    const float* __restrict__ Wih_f, const float* __restrict__ Whh_f,
    const float* __restrict__ bih_f, const float* __restrict__ bhh_f,
    const float* __restrict__ Wih_b, const float* __restrict__ Whh_b,
    const float* __restrict__ bih_b, const float* __restrict__ bhh_b,
    const float* __restrict__ Wih_m, const float* __restrict__ Whh_m,
    const float* __restrict__ bih_m, const float* __restrict__ bhh_m,
    h16* __restrict__ W1f, h16* __restrict__ W1b, h16* __restrict__ W2)
{
    int gtid = blockIdx.x * blockDim.x + threadIdx.x;
    int gs = gridDim.x * blockDim.x;
    // small LSTMs: W1[n=64][k=32]: k<8 x, 8..23 h, 24 bias (X col24==1), 25..31 zero
    for (int idx = gtid; idx < 64 * 32; idx += gs) {
        int n = idx >> 5, k = idx & 31;
        float a = ((n >> 4) == 2) ? 2.f * LOG2E : -LOG2E;
        float vf = 0.f, vb = 0.f;
        if (k < 8)        { vf = Wih_f[n * 8 + k];       vb = Wih_b[n * 8 + k]; }
        else if (k < 24)  { vf = Whh_f[n * 16 + k - 8];  vb = Whh_b[n * 16 + k - 8]; }
        else if (k == 24) { vf = bih_f[n] + bhh_f[n];    vb = bih_b[n] + bhh_b[n]; }
        W1f[idx] = (h16)(vf * a);
        W1b[idx] = (h16)(vb * a);
    }
    // middle LSTM: W2[n=256][k=128]: k<32 [hs_f|hs_b], 32..95 h2, 96 bias, 97..127 zero
    for (int idx = gtid; idx < 256 * 128; idx += gs) {
        int n = idx >> 7, k = idx & 127;
        float a = ((n >> 6) == 2) ? 2.f * LOG2E : -LOG2E;
        float v = 0.f;
        if (k < 32)       v = Wih_m[n * 32 + k];
        else if (k < 96)  v = Whh_m[n * 64 + k - 32];
        else if (k == 96) v = bih_m[n] + bhh_m[n];
        W2[idx] = (h16)(v * a);
    }
}

// ---------------- small LSTMs (fwd + bwd): ONE WAVE owns one (dir, 16-batch) recurrence ---
// v5: SWAPPED-OPERAND MFMA kills the LDS round-trip. z_g = mfma(A=W_g, B=state):
// C layout -> lane(q,b) holds units q*4+r of batch b (b=lane&15, q=lane>>4). The next
// step's B-frag (state) needs units (q-1)*8..(q-1)*8+7 of batch b for q=1,2 -- i.e. 2
// dwords from the lane^16 partner + 2 own dwords: ONE ds_swizzle(0x401F) pair, no LDS
// array, no barrier, no asm fence (~30cyc vs ~190 LDS RT on the serial path).
// Bonuses: cs loads are f32x4 (consecutive units/lane); hs store is one 8B h4 store per
// lane (full [16batch][16unit] coverage, no extra LDS read). RNE (h16) casts kept.
// B-frag per lane (col=b=batch, k=q*8+j): q=0: x(t) (fp32, 3-step rotating prefetch, cvt)
// q=1: h units 0..7  q=2: units 8..15  q=3: bias-one column (k=24), constant.
__global__ __launch_bounds__(256, 2) void small_lstm_kernel(
    const float* __restrict__ x,
    const float* __restrict__ h0f, const float* __restrict__ c0f,
    const float* __restrict__ h0b, const float* __restrict__ c0b,
    const h16* __restrict__ W1f, const h16* __restrict__ W1b,
    h16* __restrict__ hsf, h16* __restrict__ hsb)
{
    const int tid = threadIdx.x;
    const int wv = tid >> 6, lane = tid & 63;
    const int b = lane & 15, q = lane >> 4;

    const int wgid = blockIdx.x * 4 + wv;        // 2048 waves
    const int dir  = wgid & 1;
    const int base = (wgid >> 1) * 16;

    const float* h0 = dir ? h0b : h0f;
    const float* c0 = dir ? c0b : c0f;
    const h16* W1   = dir ? W1b : W1f;
    h16* hs = dir ? hsb : hsf;

    // W fragments (A-operand): gate g rows n=g*16+u, lane(u=b, k=q*8+j) -- same loads as
    // the old B-frags (A/B frag lane maps are identical for 16x16x32).
    half8 wf0 = *(const half8*)(W1 + (0 * 16 + b) * 32 + q * 8);
    half8 wf1 = *(const half8*)(W1 + (1 * 16 + b) * 32 + q * 8);
    half8 wf2 = *(const half8*)(W1 + (2 * 16 + b) * 32 + q * 8);
    half8 wf3 = *(const half8*)(W1 + (3 * 16 + b) * 32 + q * 8);

    // cell state: lane owns (units q*4..q*4+3, batch b) -> one f32x4 load
    f32x4 cv = *(const f32x4*)(c0 + (size_t)(base + b) * 16 + q * 4);
    float cs0 = cv[0] * (2.f * LOG2E);
    float cs1 = cv[1] * (2.f * LOG2E);
    float cs2 = cv[2] * (2.f * LOG2E);
    float cs3 = cv[3] * (2.f * LOG2E);

    const int t0 = dir ? (TT - 1) : 0;

    // initial state B-fragment
    half8 sf;
    if (q == 0) {
        const float* xp = x + ((size_t)t0 * BB + base + b) * 8;
        f32x4 u0 = *(const f32x4*)xp, u1 = *(const f32x4*)(xp + 4);
        sf[0] = (h16)u0[0]; sf[1] = (h16)u0[1]; sf[2] = (h16)u0[2]; sf[3] = (h16)u0[3];
        sf[4] = (h16)u1[0]; sf[5] = (h16)u1[1]; sf[6] = (h16)u1[2]; sf[7] = (h16)u1[3];
    } else if (q == 3) {
        sf[0] = (h16)1.f;
        sf[1] = (h16)0.f; sf[2] = (h16)0.f; sf[3] = (h16)0.f;
        sf[4] = (h16)0.f; sf[5] = (h16)0.f; sf[6] = (h16)0.f; sf[7] = (h16)0.f;
    } else {
        const float* hp = h0 + (size_t)(base + b) * 16 + (q - 1) * 8;
        f32x4 u0 = *(const f32x4*)hp, u1 = *(const f32x4*)(hp + 4);
        sf[0] = (h16)u0[0]; sf[1] = (h16)u0[1]; sf[2] = (h16)u0[2]; sf[3] = (h16)u0[3];
        sf[4] = (h16)u1[0]; sf[5] = (h16)u1[1]; sf[6] = (h16)u1[2]; sf[7] = (h16)u1[3];
    }

    // 4-slot x prefetch file: slot k holds x for target step u with u%4==k; consumed at
    // step s=u-1 (slot (j+1)&3), refilled at step s for u=s+4 (slot j). All indices
    // compile-time static under the 4x unroll (rule #20).
    f32x4 xr[4][2];
    if (q == 0) {
#pragma unroll
        for (int u = 1; u <= 3; ++u) {
            int tl = dir ? (TT - 1 - u) : u;
            const float* xp = x + ((size_t)tl * BB + base + b) * 8;
            xr[u][0] = *(const f32x4*)xp;
            xr[u][1] = *(const f32x4*)(xp + 4);
        }
    }

    for (int it = 0; it < TT / 4; ++it) {        // 54 outer iters x 4 steps
#pragma unroll
        for (int j = 0; j < 4; ++j) {
            const int s = it * 4 + j;
            const int t = dir ? (TT - 1 - s) : s;

            f32x4 z0 = {0.f, 0.f, 0.f, 0.f}, z1 = z0, z2 = z0, z3 = z0;
            z0 = __builtin_amdgcn_mfma_f32_16x16x32_f16(wf0, sf, z0, 0, 0, 0);
            z1 = __builtin_amdgcn_mfma_f32_16x16x32_f16(wf1, sf, z1, 0, 0, 0);
            z2 = __builtin_amdgcn_mfma_f32_16x16x32_f16(wf2, sf, z2, 0, 0, 0);
            z3 = __builtin_amdgcn_mfma_f32_16x16x32_f16(wf3, sf, z3, 0, 0, 0);

            // x for step s+1 from slot (j+1)&3 (loaded 3 steps ago)
            half8 xh;
            {
                const f32x4 u0 = xr[(j + 1) & 3][0], u1 = xr[(j + 1) & 3][1];
                xh[0] = (h16)u0[0]; xh[1] = (h16)u0[1]; xh[2] = (h16)u0[2]; xh[3] = (h16)u0[3];
                xh[4] = (h16)u1[0]; xh[5] = (h16)u1[1]; xh[6] = (h16)u1[2]; xh[7] = (h16)u1[3];
            }
            // refill slot j for target step s+4
            if (q == 0) {
                int ut = (s + 4 < TT) ? (s + 4) : (TT - 1);
                int tl = dir ? (TT - 1 - ut) : ut;
                const float* xp = x + ((size_t)tl * BB + base + b) * 8;
                xr[j][0] = *(const f32x4*)xp;
                xr[j][1] = *(const f32x4*)(xp + 4);
            }

            // lane (q,b): gates of (unit q*4+r, batch b)
            float hh0 = lstm_up(z0[0], z1[0], z2[0], z3[0], cs0);
            float hh1 = lstm_up(z0[1], z1[1], z2[1], z3[1], cs1);
            float hh2 = lstm_up(z0[2], z1[2], z2[2], z3[2], cs2);
            float hh3 = lstm_up(z0[3], z1[3], z2[3], z3[3], cs3);

            h4 hv;
            hv[0] = (h16)hh0; hv[1] = (h16)hh1; hv[2] = (h16)hh2; hv[3] = (h16)hh3;
            // hs(t) store: 64 lanes cover [16 batch][16 units], 8B each, coalesced
            *(h4*)(hs + ((size_t)t * BB + base + b) * 16 + q * 4) = hv;

            // lane^16 exchange: q1 <- q0 (units 0..3), q2 <- q3 (units 12..15)
            i2 pk = __builtin_bit_cast(i2, hv);
            int sp0 = __builtin_amdgcn_ds_swizzle(pk[0], 0x401F);   // lane ^ 16
            int sp1 = __builtin_amdgcn_ds_swizzle(pk[1], 0x401F);

            i4 nw;   // q1: [partner, own] = units 0..7; q2: [own, partner] = units 8..15
            nw[0] = (q == 1) ? sp0 : pk[0];
            nw[1] = (q == 1) ? sp1 : pk[1];
            nw[2] = (q == 1) ? pk[0] : sp0;
            nw[3] = (q == 1) ? pk[1] : sp1;
            half8 nf = __builtin_bit_cast(half8, nw);

            if (q == 0)      sf = xh;
            else if (q != 3) sf = nf;    // q==3 keeps its constant bias column
        }
    }
}

// ---------------- middle LSTM + dense, 16-batch blocks, K=96 + bias-in-acc ---------------
// (r2 version verbatim -- best measured 351.6us. r4's 2-window ILP regressed +31us:
// halving barrier-domains/waves per CU costs more than intra-wave ILP buys.)
// block = 256 (4 waves): wave w handles units [16w,16w+16) for all 4 gates.
// K-tile 3 removed -> acc init'd with (h16, pre-scaled) bias: 12 MFMA/step/wave.
// X[16][96] fp16 (+pad to 104), double-buffered; one barrier per step.
// Dense out(t-1) = 2 extra MFMA on wave 3 over X(t) k=32..95.
__global__ __launch_bounds__(256, 4) void mid_lstm_kernel(
    const h16* __restrict__ hsf, const h16* __restrict__ hsb,
    const float* __restrict__ h0m, const float* __restrict__ c0m,
    const h16* __restrict__ W2,
    const float* __restrict__ Wd, const float* __restrict__ bdp,
    float* __restrict__ out)
{
    __shared__ __attribute__((aligned(16))) h16 Xs[2][16][104];
    __shared__ float outbuf[16][55];

    const int tid = threadIdx.x;
    const int base = blockIdx.x * 16;
    const int wv = tid >> 6, lane = tid & 63, col = lane & 15, q = lane >> 4;

    half8 bfr[4][3];
    float bp[4];
#pragma unroll
    for (int p = 0; p < 4; ++p) {
        int n = p * 64 + wv * 16 + col;
#pragma unroll
        for (int kt = 0; kt < 3; ++kt)
            bfr[p][kt] = *(const half8*)(W2 + (size_t)n * 128 + kt * 32 + q * 8);
        bp[p] = (float)W2[(size_t)n * 128 + 96];   // pre-scaled bias (h16-rounded)
    }
    half8 dfr[2];   // dense B-fragment: column 0 = wd over k in [32,96)
#pragma unroll
    for (int kt = 0; kt < 2; ++kt)
#pragma unroll
        for (int j = 0; j < 8; ++j)
            dfr[kt][j] = (col == 0) ? (h16)Wd[kt * 32 + q * 8 + j] : (h16)0.f;
    const float bdv = bdp[0];

    float cs[4];
#pragma unroll
    for (int r = 0; r < 4; ++r)
        cs[r] = c0m[(size_t)(base + q * 4 + r) * 64 + wv * 16 + col] * (2.f * LOG2E);

    const h16* hsrc = (wv == 1) ? hsb : hsf;
    const int srow = lane >> 1, su8 = (lane & 1) * 8;
    // initial staging: hs(0) + h0m into Xs[0]   (pad cols 96..103 are never read)
    if (wv < 2 && lane < 32) {
        uint4 v = *(const uint4*)(hsrc + ((size_t)0 * BB + base + srow) * 16 + su8);
        *(uint4*)&Xs[0][srow][wv * 16 + su8] = v;
    }
    {
        int row = tid >> 4, u4 = (tid & 15) * 4;
        float4 v = *(const float4*)(h0m + (size_t)(base + row) * 64 + u4);
        h16* d = &Xs[0][row][32 + u4];
        d[0] = (h16)v.x; d[1] = (h16)v.y; d[2] = (h16)v.z; d[3] = (h16)v.w;
    }
    // hs register pipeline (2 steps deep) on waves 0,1
    uint4 ra, rb;
    if (wv < 2 && lane < 32) {
        ra = *(const uint4*)(hsrc + ((size_t)1 * BB + base + srow) * 16 + su8);
        rb = *(const uint4*)(hsrc + ((size_t)2 * BB + base + srow) * 16 + su8);
    }
    __syncthreads();

    for (int t = 0; t < TT; ++t) {
        const int cur = t & 1, nxt = cur ^ 1;
        if (wv < 2 && lane < 32) {
            if (t < TT - 1)
                *(uint4*)&Xs[nxt][srow][wv * 16 + su8] = ra;   // hs(t+1)
            ra = rb;
            int tl = (t + 3 < TT) ? (t + 3) : (TT - 1);
            rb = *(const uint4*)(hsrc + ((size_t)tl * BB + base + srow) * 16 + su8);
        }
        half8 af[3];
#pragma unroll
        for (int kt = 0; kt < 3; ++kt)
            af[kt] = *(const half8*)&Xs[cur][col][kt * 32 + q * 8];
        // dense for out(t-1): X(t) k=32..95 holds h2(t-1)
        if (wv == 3 && t > 0) {
            f32x4 z = {0.f, 0.f, 0.f, 0.f};
            z = __builtin_amdgcn_mfma_f32_16x16x32_f16(af[1], dfr[0], z, 0, 0, 0);
            z = __builtin_amdgcn_mfma_f32_16x16x32_f16(af[2], dfr[1], z, 0, 0, 0);
            if (col == 0) {
                int tc = (t - 1) % 54;
#pragma unroll
                for (int r = 0; r < 4; ++r)
                    outbuf[q * 4 + r][tc] = z[r] + bdv;
            }
        }
        f32x4 acc[4];
#pragma unroll
        for (int p = 0; p < 4; ++p) {
            f32x4 z = {bp[p], bp[p], bp[p], bp[p]};
            z = __builtin_amdgcn_mfma_f32_16x16x32_f16(af[0], bfr[p][0], z, 0, 0, 0);
            z = __builtin_amdgcn_mfma_f32_16x16x32_f16(af[1], bfr[p][1], z, 0, 0, 0);
            z = __builtin_amdgcn_mfma_f32_16x16x32_f16(af[2], bfr[p][2], z, 0, 0, 0);
            acc[p] = z;
        }
#pragma unroll
        for (int r = 0; r < 4; ++r) {
            float h = lstm_up(acc[0][r], acc[1][r], acc[2][r], acc[3][r], cs[r]);
            Xs[nxt][q * 4 + r][32 + wv * 16 + col] = (h16)h;
        }
        if (t > 0 && (t % 54) == 0) {   // flush out(t-54 .. t-1)
            __syncthreads();
            int off = t - 54;
            for (int idx = tid; idx < 16 * 54; idx += 256) {
                int row = idx / 54, cc = idx - row * 54;
                out[(size_t)(base + row) * TT + off + cc] = outbuf[row][cc];
            }
        }
        __syncthreads();
    }
    // epilogue: out(215) from Xs[0] (h2(215) staged there at t=215)
    if (wv == 3) {
        half8 a1 = *(const half8*)&Xs[0][col][32 + q * 8];
        half8 a2 = *(const half8*)&Xs[0][col][64 + q * 8];
        f32x4 z = {0.f, 0.f, 0.f, 0.f};
        z = __builtin_amdgcn_mfma_f32_16x16x32_f16(a1, dfr[0], z, 0, 0, 0);
        z = __builtin_amdgcn_mfma_f32_16x16x32_f16(a2, dfr[1], z, 0, 0, 0);
        if (col == 0)
#pragma unroll
            for (int r = 0; r < 4; ++r)
                outbuf[q * 4 + r][53] = z[r] + bdv;
    }
    __syncthreads();
    for (int idx = tid; idx < 16 * 54; idx += 256) {
        int row = idx / 54, cc = idx - row * 54;
        out[(size_t)(base + row) * TT + 162 + cc] = outbuf[row][cc];
    }
}

extern "C" void kernel_launch(void* const* d_in, const int* in_sizes, int n_in,
                              void* d_out, int out_size, void* d_ws, size_t ws_size,
                              hipStream_t stream)
{
    const float* x     = (const float*)d_in[0];
    const float* h0f   = (const float*)d_in[1];
    const float* c0f   = (const float*)d_in[2];
    const float* h0b   = (const float*)d_in[3];
    const float* c0b   = (const float*)d_in[4];
    const float* h0m   = (const float*)d_in[5];
    const float* c0m   = (const float*)d_in[6];
    const float* Wih_f = (const float*)d_in[7];
    const float* Whh_f = (const float*)d_in[8];
    const float* bih_f = (const float*)d_in[9];
    const float* bhh_f = (const float*)d_in[10];
    const float* Wih_b = (const float*)d_in[11];
    const float* Whh_b = (const float*)d_in[12];
    const float* bih_b = (const float*)d_in[13];
    const float* bhh_b = (const float*)d_in[14];
    const float* Wih_m = (const float*)d_in[15];
    const float* Whh_m = (const float*)d_in[16];
    const float* bih_m = (const float*)d_in[17];
    const float* bhh_m = (const float*)d_in[18];
    const float* Wd    = (const float*)d_in[19];
    const float* bd    = (const float*)d_in[20];

    char* ws = (char*)d_ws;
    h16* W1f = (h16*)(ws + 0);        // 64*32*2    = 4096
    h16* W1b = (h16*)(ws + 4096);     // 4096
    h16* W2  = (h16*)(ws + 8192);     // 256*128*2  = 65536
    h16* hsf = (h16*)(ws + 73728);                               // [T][B][16] fp16
    h16* hsb = (h16*)(ws + 73728 + (size_t)TT * BB * 16 * 2);    // [T][B][16] fp16

    prep_kernel<<<64, 256, 0, stream>>>(Wih_f, Whh_f, bih_f, bhh_f,
                                        Wih_b, Whh_b, bih_b, bhh_b,
                                        Wih_m, Whh_m, bih_m, bhh_m,
                                        W1f, W1b, W2);
    small_lstm_kernel<<<512, 256, 0, stream>>>(x, h0f, c0f, h0b, c0b,
                                               W1f, W1b, hsf, hsb);
    mid_lstm_kernel<<<1024, 256, 0, stream>>>(hsf, hsb, h0m, c0m, W2,
                                              Wd, bd, (float*)d_out);
}